// Round 1
// baseline (1101.379 us; speedup 1.0000x reference)
//
#include <hip/hip_runtime.h>

// ---------------------------------------------------------------------------
// 2-layer GCN, restructured:
//   A_hat = D^-1/2 (A + I) D^-1/2, deg from dst index (+1 self loop)
//   out = (A_hat relu((A_hat x) W1 + b1) W2) + b2     [W1 commuted out of agg]
// dinv factoring: agg(v)[i] = dinv[i] * ( sum_{src->i} v[src]*dinv[src] + v[i]*dinv[i] )
// ---------------------------------------------------------------------------

// Detect whether edge_index arrived as int64 (odd 32-bit words all zero) or int32.
static __global__ void detect64_kernel(const unsigned int* __restrict__ w, int* flag) {
    __shared__ int nz;
    if (threadIdx.x == 0) nz = 0;
    __syncthreads();
    int local = 0;
    for (int k = threadIdx.x; k < 4096; k += blockDim.x)
        if (w[2 * k + 1] != 0u) local = 1;
    if (local) atomicOr(&nz, 1);
    __syncthreads();
    if (threadIdx.x == 0) *flag = (nz == 0) ? 1 : 0;  // 1 => int64 encoding
}

static __global__ void deg_kernel(const void* __restrict__ ei, const int* __restrict__ flag,
                                  unsigned int* __restrict__ cnt, int n_edges) {
    const int is64 = *flag;
    const long long* e64 = (const long long*)ei;
    const int* e32 = (const int*)ei;
    int stride = gridDim.x * blockDim.x;
    for (int e = blockIdx.x * blockDim.x + threadIdx.x; e < n_edges; e += stride) {
        int d = is64 ? (int)e64[n_edges + e] : e32[n_edges + e];
        atomicAdd(&cnt[d], 1u);
    }
}

// Per node: dinv, xs = x*dinv, seed accx with self-loop contribution (= xs).
static __global__ void node1_kernel(const float* __restrict__ x, const unsigned int* __restrict__ cnt,
                                    float* __restrict__ dinv, float* __restrict__ xs,
                                    float* __restrict__ accx, int n_nodes) {
    int i = blockIdx.x * blockDim.x + threadIdx.x;
    if (i >= n_nodes) return;
    float di = rsqrtf((float)(cnt[i] + 1u));
    dinv[i] = di;
#pragma unroll
    for (int j = 0; j < 10; j++) {
        float v = x[i * 10 + j] * di;
        xs[i * 10 + j] = v;
        accx[i * 10 + j] = v;
    }
}

// Layer-1 scatter: 10 threads per edge, accx[dst][j] += xs[src][j].
static __global__ void edge1_kernel(const void* __restrict__ ei, const int* __restrict__ flag,
                                    const float* __restrict__ xs, float* __restrict__ accx,
                                    int n_edges) {
    const int is64 = *flag;
    const long long* e64 = (const long long*)ei;
    const int* e32 = (const int*)ei;
    unsigned int total = (unsigned int)n_edges * 10u;
    unsigned int stride = gridDim.x * blockDim.x;
    for (unsigned int t = blockIdx.x * blockDim.x + threadIdx.x; t < total; t += stride) {
        unsigned int e = t / 10u;
        unsigned int j = t - e * 10u;
        int s = is64 ? (int)e64[e] : e32[e];
        int d = is64 ? (int)e64[n_edges + e] : e32[n_edges + e];
        atomicAdd(&accx[(unsigned int)d * 10u + j], xs[(unsigned int)s * 10u + j]);
    }
}

// Per node: h1 = (dinv*accx)@W1 + b1, relu, g = h1@W2, gs = g*dinv; seed out.
static __global__ void node2_kernel(const float* __restrict__ accx, const float* __restrict__ dinv,
                                    const float* __restrict__ W1, const float* __restrict__ b1,
                                    const float* __restrict__ W2,
                                    float* __restrict__ gs, float* __restrict__ out, int n_nodes) {
    __shared__ float sW1[160];
    __shared__ float sb1[16];
    __shared__ float sW2[32];
    for (int k = threadIdx.x; k < 160; k += blockDim.x) sW1[k] = W1[k];
    if (threadIdx.x < 16) sb1[threadIdx.x] = b1[threadIdx.x];
    if (threadIdx.x < 32) sW2[threadIdx.x] = W2[threadIdx.x];
    __syncthreads();
    int i = blockIdx.x * blockDim.x + threadIdx.x;
    if (i >= n_nodes) return;
    float di = dinv[i];
    float a[10];
#pragma unroll
    for (int k = 0; k < 10; k++) a[k] = accx[i * 10 + k] * di;
    float g0 = 0.f, g1 = 0.f;
#pragma unroll
    for (int j = 0; j < 16; j++) {
        float h = sb1[j];
#pragma unroll
        for (int k = 0; k < 10; k++) h = fmaf(a[k], sW1[k * 16 + j], h);
        h = fmaxf(h, 0.f);
        g0 = fmaf(h, sW2[j * 2 + 0], g0);
        g1 = fmaf(h, sW2[j * 2 + 1], g1);
    }
    float o0 = g0 * di, o1 = g1 * di;
    gs[i * 2 + 0] = o0;
    gs[i * 2 + 1] = o1;
    out[i * 2 + 0] = o0;   // self-loop seed
    out[i * 2 + 1] = o1;
}

// Layer-2 scatter: 2 threads per edge, out[dst][k] += gs[src][k].
static __global__ void edge2_kernel(const void* __restrict__ ei, const int* __restrict__ flag,
                                    const float* __restrict__ gs, float* __restrict__ out,
                                    int n_edges) {
    const int is64 = *flag;
    const long long* e64 = (const long long*)ei;
    const int* e32 = (const int*)ei;
    unsigned int total = (unsigned int)n_edges * 2u;
    unsigned int stride = gridDim.x * blockDim.x;
    for (unsigned int t = blockIdx.x * blockDim.x + threadIdx.x; t < total; t += stride) {
        unsigned int e = t >> 1;
        unsigned int k = t & 1u;
        int s = is64 ? (int)e64[e] : e32[e];
        int d = is64 ? (int)e64[n_edges + e] : e32[n_edges + e];
        atomicAdd(&out[(unsigned int)d * 2u + k], gs[(unsigned int)s * 2u + k]);
    }
}

static __global__ void final_kernel(float* __restrict__ out, const float* __restrict__ dinv,
                                    const float* __restrict__ b2, int n2) {
    int t = blockIdx.x * blockDim.x + threadIdx.x;
    if (t < n2) out[t] = fmaf(dinv[t >> 1], out[t], b2[t & 1]);
}

extern "C" void kernel_launch(void* const* d_in, const int* in_sizes, int n_in,
                              void* d_out, int out_size, void* d_ws, size_t ws_size,
                              hipStream_t stream) {
    const float* x  = (const float*)d_in[0];
    const void*  ei = d_in[1];
    const float* W1 = (const float*)d_in[2];
    const float* b1 = (const float*)d_in[3];
    const float* W2 = (const float*)d_in[4];
    const float* b2 = (const float*)d_in[5];
    float* out = (float*)d_out;

    const int n_nodes = in_sizes[0] / 10;
    const int n_edges = in_sizes[1] / 2;

    // workspace layout
    char* p = (char*)d_ws;
    int* flag = (int*)p;                 p += 256;
    unsigned int* cnt = (unsigned int*)p; p += (size_t)n_nodes * 4;
    float* dinv = (float*)p;             p += (size_t)n_nodes * 4;
    float* gs = (float*)p;               p += (size_t)n_nodes * 2 * 4;
    float* xs = (float*)p;               p += (size_t)n_nodes * 10 * 4;
    float* accx = (float*)p;             p += (size_t)n_nodes * 10 * 4;
    (void)ws_size; (void)n_in; (void)out_size;

    hipMemsetAsync(cnt, 0, (size_t)n_nodes * 4, stream);

    detect64_kernel<<<1, 256, 0, stream>>>((const unsigned int*)ei, flag);

    {
        int blocks = 2048;
        deg_kernel<<<blocks, 256, 0, stream>>>(ei, flag, cnt, n_edges);
    }
    {
        int blocks = (n_nodes + 255) / 256;
        node1_kernel<<<blocks, 256, 0, stream>>>(x, cnt, dinv, xs, accx, n_nodes);
    }
    {
        int blocks = 4096;
        edge1_kernel<<<blocks, 256, 0, stream>>>(ei, flag, xs, accx, n_edges);
    }
    {
        int blocks = (n_nodes + 255) / 256;
        node2_kernel<<<blocks, 256, 0, stream>>>(accx, dinv, W1, b1, W2, gs, out, n_nodes);
    }
    {
        int blocks = 2048;
        edge2_kernel<<<blocks, 256, 0, stream>>>(ei, flag, gs, out, n_edges);
    }
    {
        int blocks = (n_nodes * 2 + 255) / 256;
        final_kernel<<<blocks, 256, 0, stream>>>(out, dinv, b2, n_nodes * 2);
    }
}

// Round 2
// 934.332 us; speedup vs baseline: 1.1788x; 1.1788x over previous
//
#include <hip/hip_runtime.h>

// ---------------------------------------------------------------------------
// 2-layer GCN via on-device CSR build + gather aggregation (no fp32 atomics).
//   out = dinv * (A (relu((dinv*(A' xs)) W1 + b1) W2 * dinv)) + b2
// where xs = x*dinv and A includes the self loop (folded in as a seed term).
// CSR: deg histogram -> block-aggregated row allocation -> scatter fill.
// Gathers: one 64-lane wave per node; avg degree 64 matches wave width.
// ---------------------------------------------------------------------------

static __device__ __forceinline__ int get_src(const void* ei, int is64, int n_edges, unsigned e) {
    return is64 ? (int)((const long long*)ei)[e] : ((const int*)ei)[e];
}
static __device__ __forceinline__ int get_dst(const void* ei, int is64, int n_edges, unsigned e) {
    return is64 ? (int)((const long long*)ei)[(unsigned)n_edges + e]
                : ((const int*)ei)[(unsigned)n_edges + e];
}

// Detect whether edge_index arrived as int64 (odd 32-bit words all zero) or int32.
static __global__ void detect64_kernel(const unsigned int* __restrict__ w, int* flag) {
    __shared__ int nz;
    if (threadIdx.x == 0) nz = 0;
    __syncthreads();
    int local = 0;
    for (int k = threadIdx.x; k < 4096; k += blockDim.x)
        if (w[2 * k + 1] != 0u) local = 1;
    if (local) atomicOr(&nz, 1);
    __syncthreads();
    if (threadIdx.x == 0) *flag = (nz == 0) ? 1 : 0;  // 1 => int64 encoding
}

static __global__ void deg_kernel(const void* __restrict__ ei, const int* __restrict__ flag,
                                  unsigned int* __restrict__ cnt, int n_edges) {
    const int is64 = *flag;
    unsigned stride = gridDim.x * blockDim.x;
    for (unsigned e = blockIdx.x * blockDim.x + threadIdx.x; e < (unsigned)n_edges; e += stride) {
        int d = get_dst(ei, is64, n_edges, e);
        atomicAdd(&cnt[d], 1u);
    }
}

// Row allocation: block-aggregated atomic on a single cursor (391 atomics).
static __global__ void alloc_kernel(const unsigned int* __restrict__ cnt,
                                    unsigned int* __restrict__ row_start,
                                    unsigned int* __restrict__ cursor,
                                    unsigned int* __restrict__ gcur, int n_nodes) {
    __shared__ unsigned wsum[4];
    int i = blockIdx.x * blockDim.x + threadIdx.x;
    int lane = threadIdx.x & 63;
    int wid = threadIdx.x >> 6;
    unsigned d = (i < n_nodes) ? cnt[i] : 0u;
    unsigned scan = d;
#pragma unroll
    for (int off = 1; off < 64; off <<= 1) {
        unsigned t = __shfl_up(scan, off);
        if (lane >= off) scan += t;
    }
    if (lane == 63) wsum[wid] = scan;
    __syncthreads();
    if (threadIdx.x == 0) {
        unsigned s0 = wsum[0], s1 = wsum[1], s2 = wsum[2], s3 = wsum[3];
        unsigned base = atomicAdd(gcur, s0 + s1 + s2 + s3);
        wsum[0] = base;
        wsum[1] = base + s0;
        wsum[2] = base + s0 + s1;
        wsum[3] = base + s0 + s1 + s2;
    }
    __syncthreads();
    if (i < n_nodes) {
        unsigned pos = wsum[wid] + scan - d;
        row_start[i] = pos;
        cursor[i] = pos;
    }
}

static __global__ void csrfill_kernel(const void* __restrict__ ei, const int* __restrict__ flag,
                                      unsigned int* __restrict__ cursor,
                                      unsigned int* __restrict__ csr_src, int n_edges) {
    const int is64 = *flag;
    unsigned stride = gridDim.x * blockDim.x;
    for (unsigned e = blockIdx.x * blockDim.x + threadIdx.x; e < (unsigned)n_edges; e += stride) {
        int s = get_src(ei, is64, n_edges, e);
        int d = get_dst(ei, is64, n_edges, e);
        unsigned pos = atomicAdd(&cursor[d], 1u);
        csr_src[pos] = (unsigned)s;
    }
}

// Per node: dinv, xs = x*dinv padded to 12 floats (48B rows -> float4 loads).
static __global__ void node1_kernel(const float* __restrict__ x, const unsigned int* __restrict__ cnt,
                                    float* __restrict__ dinv, float* __restrict__ xs, int n_nodes) {
    int i = blockIdx.x * blockDim.x + threadIdx.x;
    if (i >= n_nodes) return;
    float di = rsqrtf((float)(cnt[i] + 1u));
    dinv[i] = di;
    float v[12];
#pragma unroll
    for (int j = 0; j < 10; j++) v[j] = x[i * 10 + j] * di;
    v[10] = 0.f; v[11] = 0.f;
    float4* xr = (float4*)(xs + (size_t)i * 12);
    xr[0] = make_float4(v[0], v[1], v[2], v[3]);
    xr[1] = make_float4(v[4], v[5], v[6], v[7]);
    xr[2] = make_float4(v[8], v[9], v[10], v[11]);
}

// Layer-1 gather: one wave per node, lanes stride the CSR row.
static __global__ void gather1_kernel(const unsigned int* __restrict__ row_start,
                                      const unsigned int* __restrict__ cnt,
                                      const unsigned int* __restrict__ csr_src,
                                      const float* __restrict__ xs,
                                      float* __restrict__ accx, int n_nodes) {
    int w = blockIdx.x * (blockDim.x >> 6) + (threadIdx.x >> 6);
    int lane = threadIdx.x & 63;
    if (w >= n_nodes) return;
    unsigned start = row_start[w];
    unsigned degn = cnt[w];
    float acc[10];
#pragma unroll
    for (int j = 0; j < 10; j++) acc[j] = 0.f;
    const float4* X = (const float4*)xs;
    for (unsigned k = lane; k < degn; k += 64) {
        unsigned s = csr_src[start + k];
        float4 v0 = X[s * 3 + 0];
        float4 v1 = X[s * 3 + 1];
        float4 v2 = X[s * 3 + 2];
        acc[0] += v0.x; acc[1] += v0.y; acc[2] += v0.z; acc[3] += v0.w;
        acc[4] += v1.x; acc[5] += v1.y; acc[6] += v1.z; acc[7] += v1.w;
        acc[8] += v2.x; acc[9] += v2.y;
    }
#pragma unroll
    for (int off = 32; off > 0; off >>= 1) {
#pragma unroll
        for (int j = 0; j < 10; j++) acc[j] += __shfl_down(acc[j], off);
    }
    if (lane == 0) {
        const float* xsr = xs + (size_t)w * 12;   // self-loop contribution
        float4* A = (float4*)(accx + (size_t)w * 12);
        A[0] = make_float4(acc[0] + xsr[0], acc[1] + xsr[1], acc[2] + xsr[2], acc[3] + xsr[3]);
        A[1] = make_float4(acc[4] + xsr[4], acc[5] + xsr[5], acc[6] + xsr[6], acc[7] + xsr[7]);
        A[2] = make_float4(acc[8] + xsr[8], acc[9] + xsr[9], 0.f, 0.f);
    }
}

// Per node: h1 = (dinv*accx)@W1 + b1, relu, g = h1@W2, gs = g*dinv.
static __global__ void node2_kernel(const float* __restrict__ accx, const float* __restrict__ dinv,
                                    const float* __restrict__ W1, const float* __restrict__ b1,
                                    const float* __restrict__ W2,
                                    float* __restrict__ gs, int n_nodes) {
    __shared__ float sW1[160];
    __shared__ float sb1[16];
    __shared__ float sW2[32];
    for (int k = threadIdx.x; k < 160; k += blockDim.x) sW1[k] = W1[k];
    if (threadIdx.x < 16) sb1[threadIdx.x] = b1[threadIdx.x];
    if (threadIdx.x < 32) sW2[threadIdx.x] = W2[threadIdx.x];
    __syncthreads();
    int i = blockIdx.x * blockDim.x + threadIdx.x;
    if (i >= n_nodes) return;
    float di = dinv[i];
    float a[10];
#pragma unroll
    for (int k = 0; k < 10; k++) a[k] = accx[(size_t)i * 12 + k] * di;
    float g0 = 0.f, g1 = 0.f;
#pragma unroll
    for (int j = 0; j < 16; j++) {
        float h = sb1[j];
#pragma unroll
        for (int k = 0; k < 10; k++) h = fmaf(a[k], sW1[k * 16 + j], h);
        h = fmaxf(h, 0.f);
        g0 = fmaf(h, sW2[j * 2 + 0], g0);
        g1 = fmaf(h, sW2[j * 2 + 1], g1);
    }
    gs[(size_t)i * 2 + 0] = g0 * di;
    gs[(size_t)i * 2 + 1] = g1 * di;
}

// Layer-2 gather + final scale + bias, fused.
static __global__ void gather2_kernel(const unsigned int* __restrict__ row_start,
                                      const unsigned int* __restrict__ cnt,
                                      const unsigned int* __restrict__ csr_src,
                                      const float* __restrict__ gs,
                                      const float* __restrict__ dinv,
                                      const float* __restrict__ b2,
                                      float* __restrict__ out, int n_nodes) {
    int w = blockIdx.x * (blockDim.x >> 6) + (threadIdx.x >> 6);
    int lane = threadIdx.x & 63;
    if (w >= n_nodes) return;
    unsigned start = row_start[w];
    unsigned degn = cnt[w];
    float a0 = 0.f, a1 = 0.f;
    const float2* G = (const float2*)gs;
    for (unsigned k = lane; k < degn; k += 64) {
        unsigned s = csr_src[start + k];
        float2 v = G[s];
        a0 += v.x; a1 += v.y;
    }
#pragma unroll
    for (int off = 32; off > 0; off >>= 1) {
        a0 += __shfl_down(a0, off);
        a1 += __shfl_down(a1, off);
    }
    if (lane == 0) {
        float2 self = G[w];
        float di = dinv[w];
        float2 o;
        o.x = fmaf(a0 + self.x, di, b2[0]);
        o.y = fmaf(a1 + self.y, di, b2[1]);
        ((float2*)out)[w] = o;
    }
}

// ---------------- fallback (R1 atomic path, used if ws too small) ----------
static __global__ void fb_node1(const float* __restrict__ x, const unsigned int* __restrict__ cnt,
                                float* __restrict__ dinv, float* __restrict__ xs,
                                float* __restrict__ accx, int n_nodes) {
    int i = blockIdx.x * blockDim.x + threadIdx.x;
    if (i >= n_nodes) return;
    float di = rsqrtf((float)(cnt[i] + 1u));
    dinv[i] = di;
#pragma unroll
    for (int j = 0; j < 10; j++) {
        float v = x[i * 10 + j] * di;
        xs[i * 10 + j] = v;
        accx[i * 10 + j] = v;
    }
}
static __global__ void fb_edge1(const void* __restrict__ ei, const int* __restrict__ flag,
                                const float* __restrict__ xs, float* __restrict__ accx, int n_edges) {
    const int is64 = *flag;
    unsigned total = (unsigned)n_edges * 10u;
    unsigned stride = gridDim.x * blockDim.x;
    for (unsigned t = blockIdx.x * blockDim.x + threadIdx.x; t < total; t += stride) {
        unsigned e = t / 10u, j = t - e * 10u;
        int s = get_src(ei, is64, n_edges, e);
        int d = get_dst(ei, is64, n_edges, e);
        atomicAdd(&accx[(unsigned)d * 10u + j], xs[(unsigned)s * 10u + j]);
    }
}
static __global__ void fb_node2(const float* __restrict__ accx, const float* __restrict__ dinv,
                                const float* __restrict__ W1, const float* __restrict__ b1,
                                const float* __restrict__ W2,
                                float* __restrict__ gs, float* __restrict__ out, int n_nodes) {
    __shared__ float sW1[160];
    __shared__ float sb1[16];
    __shared__ float sW2[32];
    for (int k = threadIdx.x; k < 160; k += blockDim.x) sW1[k] = W1[k];
    if (threadIdx.x < 16) sb1[threadIdx.x] = b1[threadIdx.x];
    if (threadIdx.x < 32) sW2[threadIdx.x] = W2[threadIdx.x];
    __syncthreads();
    int i = blockIdx.x * blockDim.x + threadIdx.x;
    if (i >= n_nodes) return;
    float di = dinv[i];
    float a[10];
#pragma unroll
    for (int k = 0; k < 10; k++) a[k] = accx[i * 10 + k] * di;
    float g0 = 0.f, g1 = 0.f;
#pragma unroll
    for (int j = 0; j < 16; j++) {
        float h = sb1[j];
#pragma unroll
        for (int k = 0; k < 10; k++) h = fmaf(a[k], sW1[k * 16 + j], h);
        h = fmaxf(h, 0.f);
        g0 = fmaf(h, sW2[j * 2 + 0], g0);
        g1 = fmaf(h, sW2[j * 2 + 1], g1);
    }
    float o0 = g0 * di, o1 = g1 * di;
    gs[i * 2 + 0] = o0; gs[i * 2 + 1] = o1;
    out[i * 2 + 0] = o0; out[i * 2 + 1] = o1;
}
static __global__ void fb_edge2(const void* __restrict__ ei, const int* __restrict__ flag,
                                const float* __restrict__ gs, float* __restrict__ out, int n_edges) {
    const int is64 = *flag;
    unsigned total = (unsigned)n_edges * 2u;
    unsigned stride = gridDim.x * blockDim.x;
    for (unsigned t = blockIdx.x * blockDim.x + threadIdx.x; t < total; t += stride) {
        unsigned e = t >> 1, k = t & 1u;
        int s = get_src(ei, is64, n_edges, e);
        int d = get_dst(ei, is64, n_edges, e);
        atomicAdd(&out[(unsigned)d * 2u + k], gs[(unsigned)s * 2u + k]);
    }
}
static __global__ void fb_final(float* __restrict__ out, const float* __restrict__ dinv,
                                const float* __restrict__ b2, int n2) {
    int t = blockIdx.x * blockDim.x + threadIdx.x;
    if (t < n2) out[t] = fmaf(dinv[t >> 1], out[t], b2[t & 1]);
}

extern "C" void kernel_launch(void* const* d_in, const int* in_sizes, int n_in,
                              void* d_out, int out_size, void* d_ws, size_t ws_size,
                              hipStream_t stream) {
    const float* x  = (const float*)d_in[0];
    const void*  ei = d_in[1];
    const float* W1 = (const float*)d_in[2];
    const float* b1 = (const float*)d_in[3];
    const float* W2 = (const float*)d_in[4];
    const float* b2 = (const float*)d_in[5];
    float* out = (float*)d_out;

    const int n_nodes = in_sizes[0] / 10;
    const int n_edges = in_sizes[1] / 2;
    (void)n_in; (void)out_size;

    const size_t need = 256 + (size_t)n_nodes * (4 + 4 + 4 + 4 + 8 + 48 + 48) + (size_t)n_edges * 4;

    char* p = (char*)d_ws;
    int* flag = (int*)p;
    unsigned int* gcur = (unsigned int*)(p + 64);
    p += 256;
    unsigned int* cnt = (unsigned int*)p;       p += (size_t)n_nodes * 4;

    if (ws_size >= need) {
        unsigned int* row_start = (unsigned int*)p; p += (size_t)n_nodes * 4;
        unsigned int* cursor = (unsigned int*)p;    p += (size_t)n_nodes * 4;
        float* dinv = (float*)p;                    p += (size_t)n_nodes * 4;
        float* gs = (float*)p;                      p += (size_t)n_nodes * 8;
        float* xs = (float*)p;                      p += (size_t)n_nodes * 48;
        float* accx = (float*)p;                    p += (size_t)n_nodes * 48;
        unsigned int* csr_src = (unsigned int*)p;   p += (size_t)n_edges * 4;

        hipMemsetAsync(d_ws, 0, 256 + (size_t)n_nodes * 4, stream);  // flag, gcur, cnt
        detect64_kernel<<<1, 256, 0, stream>>>((const unsigned int*)ei, flag);
        deg_kernel<<<2048, 256, 0, stream>>>(ei, flag, cnt, n_edges);
        alloc_kernel<<<(n_nodes + 255) / 256, 256, 0, stream>>>(cnt, row_start, cursor, gcur, n_nodes);
        csrfill_kernel<<<4096, 256, 0, stream>>>(ei, flag, cursor, csr_src, n_edges);
        node1_kernel<<<(n_nodes + 255) / 256, 256, 0, stream>>>(x, cnt, dinv, xs, n_nodes);
        gather1_kernel<<<(n_nodes + 3) / 4, 256, 0, stream>>>(row_start, cnt, csr_src, xs, accx, n_nodes);
        node2_kernel<<<(n_nodes + 255) / 256, 256, 0, stream>>>(accx, dinv, W1, b1, W2, gs, n_nodes);
        gather2_kernel<<<(n_nodes + 3) / 4, 256, 0, stream>>>(row_start, cnt, csr_src, gs, dinv, b2, out, n_nodes);
    } else {
        // fallback: R1 atomic path (~10.6 MB scratch)
        float* dinv = (float*)p;  p += (size_t)n_nodes * 4;
        float* gs = (float*)p;    p += (size_t)n_nodes * 8;
        float* xs = (float*)p;    p += (size_t)n_nodes * 40;
        float* accx = (float*)p;  p += (size_t)n_nodes * 40;

        hipMemsetAsync(d_ws, 0, 256 + (size_t)n_nodes * 4, stream);
        detect64_kernel<<<1, 256, 0, stream>>>((const unsigned int*)ei, flag);
        deg_kernel<<<2048, 256, 0, stream>>>(ei, flag, cnt, n_edges);
        fb_node1<<<(n_nodes + 255) / 256, 256, 0, stream>>>(x, cnt, dinv, xs, accx, n_nodes);
        fb_edge1<<<4096, 256, 0, stream>>>(ei, flag, xs, accx, n_edges);
        fb_node2<<<(n_nodes + 255) / 256, 256, 0, stream>>>(accx, dinv, W1, b1, W2, gs, out, n_nodes);
        fb_edge2<<<2048, 256, 0, stream>>>(ei, flag, gs, out, n_edges);
        fb_final<<<(n_nodes * 2 + 255) / 256, 256, 0, stream>>>(out, dinv, b2, n_nodes * 2);
    }
}

// Round 3
// 290.153 us; speedup vs baseline: 3.7959x; 3.2201x over previous
//
#include <hip/hip_runtime.h>

// ---------------------------------------------------------------------------
// 2-layer GCN via atomic-free on-device CSR (bucketed counting sort) + gathers.
//   out = dinv * (A (relu((dinv*(A' xs)) W1 + b1) W2 * dinv)) + b2
// xs = x*dinv; self loop folded in as a seed term.
// CSR build: per-block LDS histograms over 196 dst-buckets (dst>>9) ->
// two tiny scans -> bucketed scatter (plain stores) -> per-bucket counting
// sort in LDS (also emits row_start/cnt/dinv). Zero global atomics.
// ---------------------------------------------------------------------------

#define NBK 256      // padded bucket slots (>= actual buckets, power of 2)
#define NBLKA 512    // blocks in histA/scatterA (edge partition)

static __device__ __forceinline__ int get_src(const void* ei, int is64, int n_edges, unsigned e) {
    return is64 ? (int)((const long long*)ei)[e] : ((const int*)ei)[e];
}
static __device__ __forceinline__ int get_dst(const void* ei, int is64, int n_edges, unsigned e) {
    return is64 ? (int)((const long long*)ei)[(unsigned)n_edges + e]
                : ((const int*)ei)[(unsigned)n_edges + e];
}

// Detect whether edge_index arrived as int64 (odd 32-bit words all zero) or int32.
static __global__ void detect64_kernel(const unsigned int* __restrict__ w, int* flag) {
    __shared__ int nz;
    if (threadIdx.x == 0) nz = 0;
    __syncthreads();
    int local = 0;
    for (int k = threadIdx.x; k < 4096; k += blockDim.x)
        if (w[2 * k + 1] != 0u) local = 1;
    if (local) atomicOr(&nz, 1);
    __syncthreads();
    if (threadIdx.x == 0) *flag = (nz == 0) ? 1 : 0;  // 1 => int64 encoding
}

// Per-block LDS histogram over buckets (dst >> 9).
static __global__ void histA_kernel(const void* __restrict__ ei, const int* __restrict__ flag,
                                    unsigned* __restrict__ histA, int n_edges) {
    __shared__ unsigned h[NBK];
    h[threadIdx.x] = 0u;
    __syncthreads();
    const int is64 = *flag;
    unsigned stride = gridDim.x * blockDim.x;
    for (unsigned e = blockIdx.x * blockDim.x + threadIdx.x; e < (unsigned)n_edges; e += stride) {
        int d = get_dst(ei, is64, n_edges, e);
        atomicAdd(&h[(unsigned)d >> 9], 1u);
    }
    __syncthreads();
    histA[blockIdx.x * NBK + threadIdx.x] = h[threadIdx.x];
}

// Per bucket b: exclusive scan of histA[blk][b] over blk=0..NBLKA-1; total[b].
static __global__ void scan1_kernel(unsigned* __restrict__ histA, unsigned* __restrict__ total) {
    __shared__ unsigned s0[NBLKA], s1[NBLKA];
    const int b = blockIdx.x;
    const int t = threadIdx.x;
    unsigned v0 = histA[t * NBK + b];
    unsigned v1 = histA[(t + 256) * NBK + b];
    unsigned* a = s0; unsigned* c = s1;
    a[t] = v0; a[t + 256] = v1;
    __syncthreads();
    for (int off = 1; off < NBLKA; off <<= 1) {
        for (int i = t; i < NBLKA; i += 256)
            c[i] = a[i] + (i >= off ? a[i - off] : 0u);
        __syncthreads();
        unsigned* tmp = a; a = c; c = tmp;
    }
    // a = inclusive scan
    histA[t * NBK + b] = a[t] - v0;
    histA[(t + 256) * NBK + b] = a[t + 256] - v1;
    if (t == 255) total[b] = a[NBLKA - 1];
}

// Exclusive scan of bucket totals -> bucket_base.
static __global__ void scan2_kernel(const unsigned* __restrict__ total,
                                    unsigned* __restrict__ bucket_base) {
    __shared__ unsigned s0[NBK], s1[NBK];
    const int t = threadIdx.x;
    unsigned v = total[t];
    unsigned* a = s0; unsigned* c = s1;
    a[t] = v;
    __syncthreads();
    for (int off = 1; off < NBK; off <<= 1) {
        c[t] = a[t] + (t >= off ? a[t - off] : 0u);
        __syncthreads();
        unsigned* tmp = a; a = c; c = tmp;
    }
    bucket_base[t] = a[t] - v;
}

// Scatter edges into dst-bucketed order as packed (src,dst) uint2.
static __global__ void scatterA_kernel(const void* __restrict__ ei, const int* __restrict__ flag,
                                       const unsigned* __restrict__ histA,
                                       const unsigned* __restrict__ bucket_base,
                                       uint2* __restrict__ bucketed, int n_edges) {
    __shared__ unsigned cur[NBK];
    cur[threadIdx.x] = bucket_base[threadIdx.x] + histA[blockIdx.x * NBK + threadIdx.x];
    __syncthreads();
    const int is64 = *flag;
    unsigned stride = gridDim.x * blockDim.x;
    for (unsigned e = blockIdx.x * blockDim.x + threadIdx.x; e < (unsigned)n_edges; e += stride) {
        int s = get_src(ei, is64, n_edges, e);
        int d = get_dst(ei, is64, n_edges, e);
        unsigned pos = atomicAdd(&cur[(unsigned)d >> 9], 1u);
        bucketed[pos] = make_uint2((unsigned)s, (unsigned)d);
    }
}

// Per bucket: counting sort of its edges by dst; emit csr_src, row_start, cnt, dinv.
static __global__ void passB_kernel(const uint2* __restrict__ bucketed,
                                    const unsigned* __restrict__ total,
                                    const unsigned* __restrict__ bucket_base,
                                    unsigned* __restrict__ csr_src,
                                    unsigned* __restrict__ row_start,
                                    unsigned* __restrict__ cnt,
                                    float* __restrict__ dinv, int n_nodes) {
    const int b = blockIdx.x;
    const int n0 = b << 9;
    if (n0 >= n_nodes) return;
    const int t = threadIdx.x;
    const unsigned base = bucket_base[b];
    const unsigned count = total[b];

    __shared__ unsigned h[512];
    __shared__ unsigned s0[512], s1[512];
    __shared__ unsigned cur[512];
    for (int i = t; i < 512; i += 256) h[i] = 0u;
    __syncthreads();
    for (unsigned k = t; k < count; k += 256)
        atomicAdd(&h[bucketed[base + k].y - (unsigned)n0], 1u);
    __syncthreads();
    unsigned* a = s0; unsigned* c = s1;
    for (int i = t; i < 512; i += 256) a[i] = h[i];
    __syncthreads();
    for (int off = 1; off < 512; off <<= 1) {
        for (int i = t; i < 512; i += 256)
            c[i] = a[i] + (i >= off ? a[i - off] : 0u);
        __syncthreads();
        unsigned* tmp = a; a = c; c = tmp;
    }
    // a = inclusive scan; exclusive = a[i]-h[i]
    for (int i = t; i < 512; i += 256) {
        unsigned excl = a[i] - h[i];
        cur[i] = excl;
        int n = n0 + i;
        if (n < n_nodes) {
            row_start[n] = base + excl;
            cnt[n] = h[i];
            dinv[n] = rsqrtf((float)(h[i] + 1u));
        }
    }
    __syncthreads();
    for (unsigned k = t; k < count; k += 256) {
        uint2 e = bucketed[base + k];
        unsigned pos = base + atomicAdd(&cur[e.y - (unsigned)n0], 1u);
        csr_src[pos] = e.x;
    }
}

// Per node: xs = x*dinv padded to 12 floats (48B rows -> float4 loads).
static __global__ void node1_kernel(const float* __restrict__ x, const float* __restrict__ dinv,
                                    float* __restrict__ xs, int n_nodes) {
    int i = blockIdx.x * blockDim.x + threadIdx.x;
    if (i >= n_nodes) return;
    float di = dinv[i];
    float v[12];
#pragma unroll
    for (int j = 0; j < 10; j++) v[j] = x[i * 10 + j] * di;
    v[10] = 0.f; v[11] = 0.f;
    float4* xr = (float4*)(xs + (size_t)i * 12);
    xr[0] = make_float4(v[0], v[1], v[2], v[3]);
    xr[1] = make_float4(v[4], v[5], v[6], v[7]);
    xr[2] = make_float4(v[8], v[9], v[10], v[11]);
}

// Layer-1 gather: one wave per node, lanes stride the CSR row.
static __global__ void gather1_kernel(const unsigned int* __restrict__ row_start,
                                      const unsigned int* __restrict__ cnt,
                                      const unsigned int* __restrict__ csr_src,
                                      const float* __restrict__ xs,
                                      float* __restrict__ accx, int n_nodes) {
    int w = blockIdx.x * (blockDim.x >> 6) + (threadIdx.x >> 6);
    int lane = threadIdx.x & 63;
    if (w >= n_nodes) return;
    unsigned start = row_start[w];
    unsigned degn = cnt[w];
    float acc[10];
#pragma unroll
    for (int j = 0; j < 10; j++) acc[j] = 0.f;
    const float4* X = (const float4*)xs;
    for (unsigned k = lane; k < degn; k += 64) {
        unsigned s = csr_src[start + k];
        float4 v0 = X[s * 3 + 0];
        float4 v1 = X[s * 3 + 1];
        float4 v2 = X[s * 3 + 2];
        acc[0] += v0.x; acc[1] += v0.y; acc[2] += v0.z; acc[3] += v0.w;
        acc[4] += v1.x; acc[5] += v1.y; acc[6] += v1.z; acc[7] += v1.w;
        acc[8] += v2.x; acc[9] += v2.y;
    }
#pragma unroll
    for (int off = 32; off > 0; off >>= 1) {
#pragma unroll
        for (int j = 0; j < 10; j++) acc[j] += __shfl_down(acc[j], off);
    }
    if (lane == 0) {
        const float* xsr = xs + (size_t)w * 12;   // self-loop contribution
        float4* A = (float4*)(accx + (size_t)w * 12);
        A[0] = make_float4(acc[0] + xsr[0], acc[1] + xsr[1], acc[2] + xsr[2], acc[3] + xsr[3]);
        A[1] = make_float4(acc[4] + xsr[4], acc[5] + xsr[5], acc[6] + xsr[6], acc[7] + xsr[7]);
        A[2] = make_float4(acc[8] + xsr[8], acc[9] + xsr[9], 0.f, 0.f);
    }
}

// Per node: h1 = (dinv*accx)@W1 + b1, relu, g = h1@W2, gs = g*dinv.
static __global__ void node2_kernel(const float* __restrict__ accx, const float* __restrict__ dinv,
                                    const float* __restrict__ W1, const float* __restrict__ b1,
                                    const float* __restrict__ W2,
                                    float* __restrict__ gs, int n_nodes) {
    __shared__ float sW1[160];
    __shared__ float sb1[16];
    __shared__ float sW2[32];
    for (int k = threadIdx.x; k < 160; k += blockDim.x) sW1[k] = W1[k];
    if (threadIdx.x < 16) sb1[threadIdx.x] = b1[threadIdx.x];
    if (threadIdx.x < 32) sW2[threadIdx.x] = W2[threadIdx.x];
    __syncthreads();
    int i = blockIdx.x * blockDim.x + threadIdx.x;
    if (i >= n_nodes) return;
    float di = dinv[i];
    float a[10];
#pragma unroll
    for (int k = 0; k < 10; k++) a[k] = accx[(size_t)i * 12 + k] * di;
    float g0 = 0.f, g1 = 0.f;
#pragma unroll
    for (int j = 0; j < 16; j++) {
        float h = sb1[j];
#pragma unroll
        for (int k = 0; k < 10; k++) h = fmaf(a[k], sW1[k * 16 + j], h);
        h = fmaxf(h, 0.f);
        g0 = fmaf(h, sW2[j * 2 + 0], g0);
        g1 = fmaf(h, sW2[j * 2 + 1], g1);
    }
    gs[(size_t)i * 2 + 0] = g0 * di;
    gs[(size_t)i * 2 + 1] = g1 * di;
}

// Layer-2 gather + final scale + bias, fused.
static __global__ void gather2_kernel(const unsigned int* __restrict__ row_start,
                                      const unsigned int* __restrict__ cnt,
                                      const unsigned int* __restrict__ csr_src,
                                      const float* __restrict__ gs,
                                      const float* __restrict__ dinv,
                                      const float* __restrict__ b2,
                                      float* __restrict__ out, int n_nodes) {
    int w = blockIdx.x * (blockDim.x >> 6) + (threadIdx.x >> 6);
    int lane = threadIdx.x & 63;
    if (w >= n_nodes) return;
    unsigned start = row_start[w];
    unsigned degn = cnt[w];
    float a0 = 0.f, a1 = 0.f;
    const float2* G = (const float2*)gs;
    for (unsigned k = lane; k < degn; k += 64) {
        unsigned s = csr_src[start + k];
        float2 v = G[s];
        a0 += v.x; a1 += v.y;
    }
#pragma unroll
    for (int off = 32; off > 0; off >>= 1) {
        a0 += __shfl_down(a0, off);
        a1 += __shfl_down(a1, off);
    }
    if (lane == 0) {
        float2 self = G[w];
        float di = dinv[w];
        float2 o;
        o.x = fmaf(a0 + self.x, di, b2[0]);
        o.y = fmaf(a1 + self.y, di, b2[1]);
        ((float2*)out)[w] = o;
    }
}

// ---------------- fallback (R2 atomic-CSR path, used if ws too small) ------
static __global__ void deg_kernel(const void* __restrict__ ei, const int* __restrict__ flag,
                                  unsigned int* __restrict__ cnt, int n_edges) {
    const int is64 = *flag;
    unsigned stride = gridDim.x * blockDim.x;
    for (unsigned e = blockIdx.x * blockDim.x + threadIdx.x; e < (unsigned)n_edges; e += stride) {
        int d = get_dst(ei, is64, n_edges, e);
        atomicAdd(&cnt[d], 1u);
    }
}
static __global__ void alloc_kernel(const unsigned int* __restrict__ cnt,
                                    unsigned int* __restrict__ row_start,
                                    unsigned int* __restrict__ cursor,
                                    unsigned int* __restrict__ gcur,
                                    float* __restrict__ dinv, int n_nodes) {
    __shared__ unsigned wsum[4];
    int i = blockIdx.x * blockDim.x + threadIdx.x;
    int lane = threadIdx.x & 63;
    int wid = threadIdx.x >> 6;
    unsigned d = (i < n_nodes) ? cnt[i] : 0u;
    unsigned scan = d;
#pragma unroll
    for (int off = 1; off < 64; off <<= 1) {
        unsigned t = __shfl_up(scan, off);
        if (lane >= off) scan += t;
    }
    if (lane == 63) wsum[wid] = scan;
    __syncthreads();
    if (threadIdx.x == 0) {
        unsigned s0 = wsum[0], s1 = wsum[1], s2 = wsum[2], s3 = wsum[3];
        unsigned base = atomicAdd(gcur, s0 + s1 + s2 + s3);
        wsum[0] = base;
        wsum[1] = base + s0;
        wsum[2] = base + s0 + s1;
        wsum[3] = base + s0 + s1 + s2;
    }
    __syncthreads();
    if (i < n_nodes) {
        unsigned pos = wsum[wid] + scan - d;
        row_start[i] = pos;
        cursor[i] = pos;
        dinv[i] = rsqrtf((float)(d + 1u));
    }
}
static __global__ void csrfill_kernel(const void* __restrict__ ei, const int* __restrict__ flag,
                                      unsigned int* __restrict__ cursor,
                                      unsigned int* __restrict__ csr_src, int n_edges) {
    const int is64 = *flag;
    unsigned stride = gridDim.x * blockDim.x;
    for (unsigned e = blockIdx.x * blockDim.x + threadIdx.x; e < (unsigned)n_edges; e += stride) {
        int s = get_src(ei, is64, n_edges, e);
        int d = get_dst(ei, is64, n_edges, e);
        unsigned pos = atomicAdd(&cursor[d], 1u);
        csr_src[pos] = (unsigned)s;
    }
}

extern "C" void kernel_launch(void* const* d_in, const int* in_sizes, int n_in,
                              void* d_out, int out_size, void* d_ws, size_t ws_size,
                              hipStream_t stream) {
    const float* x  = (const float*)d_in[0];
    const void*  ei = d_in[1];
    const float* W1 = (const float*)d_in[2];
    const float* b1 = (const float*)d_in[3];
    const float* W2 = (const float*)d_in[4];
    const float* b2 = (const float*)d_in[5];
    float* out = (float*)d_out;

    const int n_nodes = in_sizes[0] / 10;
    const int n_edges = in_sizes[1] / 2;
    (void)n_in; (void)out_size;

    // Node-side buffers common to both paths.
    const size_t node_bytes = (size_t)n_nodes * (4 + 4 + 4 + 8 + 48 + 48);
    const size_t need_new = 256 + (size_t)NBLKA * NBK * 4 + 2 * NBK * 4 + 64 +
                            node_bytes + (size_t)n_edges * 4 + (size_t)n_edges * 8;
    const size_t need_old = 256 + node_bytes + (size_t)n_nodes * 4 /*cursor*/ +
                            (size_t)n_edges * 4;
    const bool bucket_ok = (((n_nodes - 1) >> 9) + 1) <= NBK;  // 512-node buckets fit

    char* p = (char*)d_ws;
    int* flag = (int*)p;
    unsigned* gcur = (unsigned*)(p + 64);
    p += 256;
    unsigned* row_start = (unsigned*)p; p += (size_t)n_nodes * 4;
    unsigned* cnt = (unsigned*)p;       p += (size_t)n_nodes * 4;
    float* dinv = (float*)p;            p += (size_t)n_nodes * 4;
    float* gs = (float*)p;              p += (size_t)n_nodes * 8;
    float* xs = (float*)p;              p += (size_t)n_nodes * 48;
    float* accx = (float*)p;            p += (size_t)n_nodes * 48;
    unsigned* csr_src = (unsigned*)p;   p += (size_t)n_edges * 4;

    if (bucket_ok && ws_size >= need_new) {
        unsigned* histA = (unsigned*)p;       p += (size_t)NBLKA * NBK * 4;
        unsigned* total = (unsigned*)p;       p += NBK * 4;
        unsigned* bucket_base = (unsigned*)p; p += NBK * 4 + 64;
        uint2* bucketed = (uint2*)p;          p += (size_t)n_edges * 8;

        detect64_kernel<<<1, 256, 0, stream>>>((const unsigned int*)ei, flag);
        histA_kernel<<<NBLKA, 256, 0, stream>>>(ei, flag, histA, n_edges);
        scan1_kernel<<<NBK, 256, 0, stream>>>(histA, total);
        scan2_kernel<<<1, NBK, 0, stream>>>(total, bucket_base);
        scatterA_kernel<<<NBLKA, 256, 0, stream>>>(ei, flag, histA, bucket_base, bucketed, n_edges);
        passB_kernel<<<NBK, 256, 0, stream>>>(bucketed, total, bucket_base, csr_src,
                                              row_start, cnt, dinv, n_nodes);
        node1_kernel<<<(n_nodes + 255) / 256, 256, 0, stream>>>(x, dinv, xs, n_nodes);
        gather1_kernel<<<(n_nodes + 3) / 4, 256, 0, stream>>>(row_start, cnt, csr_src, xs, accx, n_nodes);
        node2_kernel<<<(n_nodes + 255) / 256, 256, 0, stream>>>(accx, dinv, W1, b1, W2, gs, n_nodes);
        gather2_kernel<<<(n_nodes + 3) / 4, 256, 0, stream>>>(row_start, cnt, csr_src, gs, dinv, b2, out, n_nodes);
    } else if (ws_size >= need_old) {
        unsigned* cursor = (unsigned*)p; p += (size_t)n_nodes * 4;

        hipMemsetAsync(d_ws, 0, 256 + (size_t)n_nodes * 4, stream);  // flag,gcur + row_start? (cnt zeroed below)
        hipMemsetAsync(cnt, 0, (size_t)n_nodes * 4, stream);
        detect64_kernel<<<1, 256, 0, stream>>>((const unsigned int*)ei, flag);
        deg_kernel<<<2048, 256, 0, stream>>>(ei, flag, cnt, n_edges);
        alloc_kernel<<<(n_nodes + 255) / 256, 256, 0, stream>>>(cnt, row_start, cursor, gcur, dinv, n_nodes);
        csrfill_kernel<<<4096, 256, 0, stream>>>(ei, flag, cursor, csr_src, n_edges);
        node1_kernel<<<(n_nodes + 255) / 256, 256, 0, stream>>>(x, dinv, xs, n_nodes);
        gather1_kernel<<<(n_nodes + 3) / 4, 256, 0, stream>>>(row_start, cnt, csr_src, xs, accx, n_nodes);
        node2_kernel<<<(n_nodes + 255) / 256, 256, 0, stream>>>(accx, dinv, W1, b1, W2, gs, n_nodes);
        gather2_kernel<<<(n_nodes + 3) / 4, 256, 0, stream>>>(row_start, cnt, csr_src, gs, dinv, b2, out, n_nodes);
    }
}